// Round 3
// baseline (41.934 us; speedup 1.0000x reference)
//
#include <hip/hip_runtime.h>

#define D_FEAT 128

// Kernel A: 8 lanes per edge (8 edges per wave64).
// Each lane loads 4x float4 from the src row and dst row. 8 lanes x 16B =
// exactly one 128B cache line per load instruction, fully consumed.
// 8 loads/lane in flight -> 8KB/wave of outstanding gather traffic.
// The reference's seg_max pass is dropped: softmax is shift-invariant and
// e = exp(-0.01*L1) is in (0,1], so exp(e) <= 2.72 cannot overflow.
__global__ void edge_eval_kernel(const float* __restrict__ feats,
                                 const int* __restrict__ src,
                                 const int* __restrict__ dst,
                                 float* __restrict__ seg_sum,
                                 float* __restrict__ out,
                                 int E) {
    int gtid = blockIdx.x * blockDim.x + threadIdx.x;
    int edge = gtid >> 3;
    int sl   = threadIdx.x & 7;    // sub-lane within the 8-lane group
    if (edge >= E) return;

    int s = src[edge];
    int d = dst[edge];

    const float4* fa = (const float4*)(feats + (size_t)s * D_FEAT);
    const float4* fb = (const float4*)(feats + (size_t)d * D_FEAT);
    // row = 32 float4; 8 lanes x 4 loads cover it
    float4 a0 = fa[sl];
    float4 a1 = fa[sl + 8];
    float4 a2 = fa[sl + 16];
    float4 a3 = fa[sl + 24];
    float4 b0 = fb[sl];
    float4 b1 = fb[sl + 8];
    float4 b2 = fb[sl + 16];
    float4 b3 = fb[sl + 24];

    float sum = fabsf(a0.x - b0.x) + fabsf(a0.y - b0.y)
              + fabsf(a0.z - b0.z) + fabsf(a0.w - b0.w)
              + fabsf(a1.x - b1.x) + fabsf(a1.y - b1.y)
              + fabsf(a1.z - b1.z) + fabsf(a1.w - b1.w)
              + fabsf(a2.x - b2.x) + fabsf(a2.y - b2.y)
              + fabsf(a2.z - b2.z) + fabsf(a2.w - b2.w)
              + fabsf(a3.x - b3.x) + fabsf(a3.y - b3.y)
              + fabsf(a3.z - b3.z) + fabsf(a3.w - b3.w);

    // reduce across the 8-lane group (stays within the wave)
    #pragma unroll
    for (int off = 4; off >= 1; off >>= 1)
        sum += __shfl_xor(sum, off, 64);

    if (sl == 0) {
        float p = expf(expf(-0.01f * sum));
        out[edge] = p;
        atomicAdd(seg_sum + d, p);
    }
}

// Kernel B: out[e] /= seg_sum[dst[e]], 4 edges per thread (float4/int4).
__global__ void edge_div_kernel(const int* __restrict__ dst,
                                const float* __restrict__ seg_sum,
                                float* __restrict__ out,
                                int E4) {
    int i = blockIdx.x * blockDim.x + threadIdx.x;
    if (i >= E4) return;
    float4 p = ((const float4*)out)[i];
    int4   d = ((const int4*)dst)[i];
    p.x /= seg_sum[d.x];
    p.y /= seg_sum[d.y];
    p.z /= seg_sum[d.z];
    p.w /= seg_sum[d.w];
    ((float4*)out)[i] = p;
}

// scalar tail (E % 4 != 0) — not hit for E=320000, kept for generality
__global__ void edge_div_tail_kernel(const int* __restrict__ dst,
                                     const float* __restrict__ seg_sum,
                                     float* __restrict__ out,
                                     int start, int E) {
    int e = start + blockIdx.x * blockDim.x + threadIdx.x;
    if (e >= E) return;
    out[e] = out[e] / seg_sum[dst[e]];
}

extern "C" void kernel_launch(void* const* d_in, const int* in_sizes, int n_in,
                              void* d_out, int out_size, void* d_ws, size_t ws_size,
                              hipStream_t stream) {
    const float* feats = (const float*)d_in[0];
    const int*   eidx  = (const int*)d_in[1];

    const int E = in_sizes[1] / 2;          // 320000
    const int N = in_sizes[0] / D_FEAT;     // 10000

    const int* src = eidx;       // edge_index row 0
    const int* dst = eidx + E;   // edge_index row 1

    float* seg_sum = (float*)d_ws;          // [N]
    float* out     = (float*)d_out;         // [E]

    hipMemsetAsync(seg_sum, 0, (size_t)N * sizeof(float), stream);

    // Kernel A: 8 lanes/edge, 256 threads/block -> 32 edges/block
    {
        dim3 blk(256);
        dim3 grd((E + 31) / 32);
        edge_eval_kernel<<<grd, blk, 0, stream>>>(feats, src, dst, seg_sum, out, E);
    }
    // Divide pass: 4 edges/thread
    {
        int E4 = E >> 2;
        if (E4 > 0) {
            dim3 blk(256);
            dim3 grd((E4 + 255) / 256);
            edge_div_kernel<<<grd, blk, 0, stream>>>(dst, seg_sum, out, E4);
        }
        if (E & 3) {
            int start = E4 << 2;
            dim3 blk(64);
            dim3 grd(1);
            edge_div_tail_kernel<<<grd, blk, 0, stream>>>(dst, seg_sum, out, start, E);
        }
    }
}

// Round 4
// 41.365 us; speedup vs baseline: 1.0138x; 1.0138x over previous
//
#include <hip/hip_runtime.h>
#include <hip/hip_fp16.h>

#define D_FEAT 128

// Prologue: convert feats f32 -> f16 (halves the gather table to 2.56 MB so
// it fits in each XCD's 4 MB L2), and zero seg_sum (folded in to save a
// dispatch). 8 elements per thread.
__global__ void convert_kernel(const float* __restrict__ feats,
                               __half* __restrict__ feats16,
                               float* __restrict__ seg_sum,
                               int total8, int N) {
    int i = blockIdx.x * blockDim.x + threadIdx.x;
    if (i < N) seg_sum[i] = 0.0f;
    if (i >= total8) return;
    float4 v0 = ((const float4*)feats)[2 * i];
    float4 v1 = ((const float4*)feats)[2 * i + 1];
    __half2 h[4];
    h[0] = __floats2half2_rn(v0.x, v0.y);
    h[1] = __floats2half2_rn(v0.z, v0.w);
    h[2] = __floats2half2_rn(v1.x, v1.y);
    h[3] = __floats2half2_rn(v1.z, v1.w);
    ((uint4*)feats16)[i] = *reinterpret_cast<uint4*>(h);
}

// |a-b| L1 over 8 f16 elements packed in a uint4, accumulated in f32.
__device__ inline float l1_u32(unsigned ua, unsigned ub) {
    __half2 ha = *reinterpret_cast<__half2*>(&ua);
    __half2 hb = *reinterpret_cast<__half2*>(&ub);
    float2 fa = __half22float2(ha);
    float2 fb = __half22float2(hb);
    return fabsf(fa.x - fb.x) + fabsf(fa.y - fb.y);
}
__device__ inline float l1_u4(uint4 a, uint4 b) {
    return l1_u32(a.x, b.x) + l1_u32(a.y, b.y)
         + l1_u32(a.z, b.z) + l1_u32(a.w, b.w);
}

// Kernel A: 8 lanes per edge (8 edges per wave64). Row = 128 f16 = 256 B =
// 16x16B; each lane loads 2x uint4 per row (8 lanes x 16 B = one 128 B line
// per load instruction). Gathers are L2-served since the f16 table is
// L2-resident per XCD. seg_max pass dropped (softmax shift invariance,
// e in (0,1] -> exp(e) <= 2.72, no overflow).
__global__ void edge_eval_kernel(const __half* __restrict__ feats16,
                                 const int* __restrict__ src,
                                 const int* __restrict__ dst,
                                 float* __restrict__ seg_sum,
                                 float* __restrict__ out,
                                 int E) {
    int gtid = blockIdx.x * blockDim.x + threadIdx.x;
    int edge = gtid >> 3;
    int sl   = threadIdx.x & 7;
    if (edge >= E) return;

    int s = src[edge];
    int d = dst[edge];

    const uint4* fa = (const uint4*)(feats16 + (size_t)s * D_FEAT);
    const uint4* fb = (const uint4*)(feats16 + (size_t)d * D_FEAT);
    uint4 a0 = fa[sl];
    uint4 a1 = fa[sl + 8];
    uint4 b0 = fb[sl];
    uint4 b1 = fb[sl + 8];

    float sum = l1_u4(a0, b0) + l1_u4(a1, b1);

    // reduce across the 8-lane group (stays within the wave)
    #pragma unroll
    for (int off = 4; off >= 1; off >>= 1)
        sum += __shfl_xor(sum, off, 64);

    if (sl == 0) {
        float p = expf(expf(-0.01f * sum));
        out[edge] = p;
        atomicAdd(seg_sum + d, p);
    }
}

// Kernel B: out[e] /= seg_sum[dst[e]], 4 edges per thread (float4/int4).
__global__ void edge_div_kernel(const int* __restrict__ dst,
                                const float* __restrict__ seg_sum,
                                float* __restrict__ out,
                                int E4) {
    int i = blockIdx.x * blockDim.x + threadIdx.x;
    if (i >= E4) return;
    float4 p = ((const float4*)out)[i];
    int4   d = ((const int4*)dst)[i];
    p.x /= seg_sum[d.x];
    p.y /= seg_sum[d.y];
    p.z /= seg_sum[d.z];
    p.w /= seg_sum[d.w];
    ((float4*)out)[i] = p;
}

// scalar tail (E % 4 != 0) — not hit for E=320000, kept for generality
__global__ void edge_div_tail_kernel(const int* __restrict__ dst,
                                     const float* __restrict__ seg_sum,
                                     float* __restrict__ out,
                                     int start, int E) {
    int e = start + blockIdx.x * blockDim.x + threadIdx.x;
    if (e >= E) return;
    out[e] = out[e] / seg_sum[dst[e]];
}

extern "C" void kernel_launch(void* const* d_in, const int* in_sizes, int n_in,
                              void* d_out, int out_size, void* d_ws, size_t ws_size,
                              hipStream_t stream) {
    const float* feats = (const float*)d_in[0];
    const int*   eidx  = (const int*)d_in[1];

    const int E = in_sizes[1] / 2;          // 320000
    const int N = in_sizes[0] / D_FEAT;     // 10000

    const int* src = eidx;       // edge_index row 0
    const int* dst = eidx + E;   // edge_index row 1

    float*  seg_sum = (float*)d_ws;                     // [N]
    __half* feats16 = (__half*)(seg_sum + ((N + 3) & ~3)); // [N*D], 16B-aligned
    float*  out     = (float*)d_out;                    // [E]

    // Prologue: f32 -> f16 table + zero seg_sum
    {
        int total8 = N * D_FEAT / 8;   // 160000
        dim3 blk(256);
        dim3 grd((total8 + 255) / 256);
        convert_kernel<<<grd, blk, 0, stream>>>(feats, feats16, seg_sum, total8, N);
    }
    // Kernel A: 8 lanes/edge, 256 threads/block -> 32 edges/block
    {
        dim3 blk(256);
        dim3 grd((E + 31) / 32);
        edge_eval_kernel<<<grd, blk, 0, stream>>>(feats16, src, dst, seg_sum, out, E);
    }
    // Divide pass: 4 edges/thread
    {
        int E4 = E >> 2;
        if (E4 > 0) {
            dim3 blk(256);
            dim3 grd((E4 + 255) / 256);
            edge_div_kernel<<<grd, blk, 0, stream>>>(dst, seg_sum, out, E4);
        }
        if (E & 3) {
            int start = E4 << 2;
            dim3 blk(64);
            dim3 grd(1);
            edge_div_tail_kernel<<<grd, blk, 0, stream>>>(dst, seg_sum, out, start, E);
        }
    }
}